// Round 5
// baseline (185.107 us; speedup 1.0000x reference)
//
#include <hip/hip_runtime.h>

#define LBL 256
#define NBINS (LBL * LBL)      // 65536 bins
#define NWORDS (NBINS / 2)     // 32768 packed u32 words (2 x u16 counters)
#define NQUADS (NWORDS / 4)    // 8192 uint4 quads (8 bins each)
#define HIST_BLOCKS 256
#define HIST_THREADS 1024

// aux layout (ints): [0]=ticket counter, [64..320)=colsum, [320..576)=colcnt,
// [576..832)=gt_size, [832..1088)=row_pairs, [1088..1344)=best_p, [1344..1600)=inter
#define AUX_COUNTER 0
#define AUX_COLSUM 64
#define AUX_COLCNT 320
#define AUX_GTSIZE 576
#define AUX_RP 832
#define AUX_BEST 1088
#define AUX_INTER 1344
#define AUX_ZERO_INTS 576      // only counter+colsum+colcnt need zeroing
#define AUX_INTS 1600

typedef int vint4 __attribute__((ext_vector_type(4)));

// ---------------- histogram with LDS privatization (packed u16 pairs) -------
// 128 KB static LDS -> 1 block/CU. Each block sees <= 65536 pixels, so a
// packed 16-bit half cannot overflow. Plain (cacheable) loads: inputs are
// L3-resident across graph replays; nontemporal defeated that. Unroll x8:
// 16 independent 16B loads in flight per thread.
__global__ __launch_bounds__(HIST_THREADS, 4)
void hist_priv_kernel(const int* __restrict__ pred, const int* __restrict__ gt,
                      unsigned int* __restrict__ partial, int* __restrict__ aux,
                      int n4, int n) {
    __shared__ unsigned int h[NWORDS];  // 128 KB
    const int t = threadIdx.x;
    if (blockIdx.x == 0 && t < AUX_ZERO_INTS) aux[t] = 0;  // consumer is next kernel
    #pragma unroll
    for (int i = t; i < NWORDS; i += HIST_THREADS) h[i] = 0u;
    __syncthreads();

    const vint4* p4 = (const vint4*)pred;
    const vint4* g4 = (const vint4*)gt;
    const int stride = HIST_BLOCKS * HIST_THREADS;
    int i = blockIdx.x * HIST_THREADS + t;
    for (; i + 7 * stride < n4; i += 8 * stride) {
        vint4 pv[8], gv[8];
        #pragma unroll
        for (int u = 0; u < 8; ++u) {
            pv[u] = p4[i + u * stride];
            gv[u] = g4[i + u * stride];
        }
        #pragma unroll
        for (int u = 0; u < 8; ++u) {
            int b;
            b = (gv[u].x << 8) | pv[u].x; atomicAdd(&h[b >> 1], 1u << ((b & 1) << 4));
            b = (gv[u].y << 8) | pv[u].y; atomicAdd(&h[b >> 1], 1u << ((b & 1) << 4));
            b = (gv[u].z << 8) | pv[u].z; atomicAdd(&h[b >> 1], 1u << ((b & 1) << 4));
            b = (gv[u].w << 8) | pv[u].w; atomicAdd(&h[b >> 1], 1u << ((b & 1) << 4));
        }
    }
    for (; i < n4; i += stride) {
        vint4 p = p4[i];
        vint4 g = g4[i];
        int b;
        b = (g.x << 8) | p.x; atomicAdd(&h[b >> 1], 1u << ((b & 1) << 4));
        b = (g.y << 8) | p.y; atomicAdd(&h[b >> 1], 1u << ((b & 1) << 4));
        b = (g.z << 8) | p.z; atomicAdd(&h[b >> 1], 1u << ((b & 1) << 4));
        b = (g.w << 8) | p.w; atomicAdd(&h[b >> 1], 1u << ((b & 1) << 4));
    }
    if (blockIdx.x == 0 && t == 0) {  // n%4 tail — dead for 4096x4096
        for (int j = n4 * 4; j < n; ++j) {
            int b = (gt[j] << 8) | pred[j];
            atomicAdd(&h[b >> 1], 1u << ((b & 1) << 4));
        }
    }
    __syncthreads();
    uint4* dst = (uint4*)(partial + (size_t)blockIdx.x * NWORDS);
    const uint4* src = (const uint4*)h;
    #pragma unroll
    for (int j = t; j < NQUADS; j += HIST_THREADS) dst[j] = src[j];
}

// ---------------- fused reduce + finalize (last-block pattern) --------------
// Block r sums the 256 packed partials for row r of C, does the row-side
// analysis (gt_size, Cnz pair count, majority match), atomicAdds its column
// contributions into aux colsum/colcnt, publishes row meta, then takes a
// ticket. The last-arriving block (all 256 rows complete) performs tallies
// and the greedy matching. No spin-wait -> no co-residency assumption.
__global__ __launch_bounds__(256)
void reduce_finalize_kernel(const unsigned int* __restrict__ partial,
                            int* __restrict__ aux, float* __restrict__ out) {
    __shared__ int acc[256];
    __shared__ int red[4], redp[4];
    __shared__ int s_gs, s_rp, s_best, s_inter, s_last;
    const int t = threadIdx.x;
    const int r = blockIdx.x;
    acc[t] = 0;
    if (t == 0) { s_best = 0; s_inter = 0; }
    __syncthreads();

    // sum 256 partials for this row's 32 quads (8 bins/quad)
    const int qlocal = t & 31;            // quad within row
    const int q = r * 32 + qlocal;        // global quad index
    const int pg = t >> 5;                // partial group 0..7 (32 partials each)
    const uint4* p4 = (const uint4*)partial;
    int s0 = 0, s1 = 0, s2 = 0, s3 = 0, s4 = 0, s5 = 0, s6 = 0, s7 = 0;
    #pragma unroll 8
    for (int k = 0; k < 32; ++k) {
        uint4 v = p4[(size_t)(pg * 32 + k) * NQUADS + q];
        s0 += (int)(v.x & 0xFFFFu); s1 += (int)(v.x >> 16);
        s2 += (int)(v.y & 0xFFFFu); s3 += (int)(v.y >> 16);
        s4 += (int)(v.z & 0xFFFFu); s5 += (int)(v.z >> 16);
        s6 += (int)(v.w & 0xFFFFu); s7 += (int)(v.w >> 16);
    }
    const int cb = qlocal * 8;
    atomicAdd(&acc[cb + 0], s0); atomicAdd(&acc[cb + 1], s1);
    atomicAdd(&acc[cb + 2], s2); atomicAdd(&acc[cb + 3], s3);
    atomicAdd(&acc[cb + 4], s4); atomicAdd(&acc[cb + 5], s5);
    atomicAdd(&acc[cb + 6], s6); atomicAdd(&acc[cb + 7], s7);
    __syncthreads();

    const int v = acc[t];                 // this row's count at col t
    // column-side accumulators (device-scope atomics; coherent at L2 point)
    if (v) atomicAdd(&aux[AUX_COLSUM + t], v);
    if (r >= 1 && t >= 1 && v > 0) atomicAdd(&aux[AUX_COLCNT + t], 1);

    // row reductions: full row sum (gt_size) + Cnz pair count
    int ssum = v;
    int pcnt = (r >= 1 && t >= 1 && v > 0) ? 1 : 0;
    #pragma unroll
    for (int m = 32; m >= 1; m >>= 1) {
        ssum += __shfl_xor(ssum, m);
        pcnt += __shfl_xor(pcnt, m);
    }
    if ((t & 63) == 0) { red[t >> 6] = ssum; redp[t >> 6] = pcnt; }
    __syncthreads();
    if (t == 0) {
        s_gs = red[0] + red[1] + red[2] + red[3];
        s_rp = redp[0] + redp[1] + redp[2] + redp[3];
    }
    __syncthreads();
    // at most one col can satisfy 2v > gs (two would sum past gs) -> plain store
    if (r >= 1 && t >= 1 && 2 * v > s_gs) { s_best = t; s_inter = v; }
    __syncthreads();
    // publish row meta, then take a ticket. __syncthreads above drained this
    // block's atomics (vmcnt(0) before s_barrier); fence orders t0's stores.
    if (t == 0) {
        aux[AUX_GTSIZE + r] = s_gs;
        aux[AUX_RP + r] = s_rp;
        aux[AUX_BEST + r] = s_best;
        aux[AUX_INTER + r] = s_inter;
        __threadfence();
        int ticket = atomicAdd(&aux[AUX_COUNTER], 1);
        s_last = (ticket == (int)gridDim.x - 1) ? 1 : 0;
    }
    __syncthreads();
    if (!s_last) return;
    __threadfence();  // acquire side

    // ---------------- finalize in the last block ----------------
    __shared__ int gt_size[LBL], pred_size[LBL], best[LBL], inter[LBL];
    __shared__ int rp_a[LBL], colcnt[LBL];
    __shared__ unsigned char used[LBL];
    __shared__ int s_ngt, s_npred, s_pairs, s_ea;
    if (t == 0) { s_ngt = 0; s_npred = 0; s_pairs = 0; s_ea = 0; }
    used[t & 255] = 0;
    gt_size[t]   = __hip_atomic_load(&aux[AUX_GTSIZE + t], __ATOMIC_RELAXED, __HIP_MEMORY_SCOPE_AGENT);
    rp_a[t]      = __hip_atomic_load(&aux[AUX_RP + t],     __ATOMIC_RELAXED, __HIP_MEMORY_SCOPE_AGENT);
    best[t]      = __hip_atomic_load(&aux[AUX_BEST + t],   __ATOMIC_RELAXED, __HIP_MEMORY_SCOPE_AGENT);
    inter[t]     = __hip_atomic_load(&aux[AUX_INTER + t],  __ATOMIC_RELAXED, __HIP_MEMORY_SCOPE_AGENT);
    pred_size[t] = __hip_atomic_load(&aux[AUX_COLSUM + t], __ATOMIC_RELAXED, __HIP_MEMORY_SCOPE_AGENT);
    colcnt[t]    = __hip_atomic_load(&aux[AUX_COLCNT + t], __ATOMIC_RELAXED, __HIP_MEMORY_SCOPE_AGENT);
    __syncthreads();
    if (t >= 1) {
        if (gt_size[t] > 0) atomicAdd(&s_ngt, 1);
        if (pred_size[t] > 0) atomicAdd(&s_npred, 1);
        if (colcnt[t] > 1) atomicAdd(&s_ea, 1);
        if (rp_a[t]) atomicAdd(&s_pairs, rp_a[t]);
    }
    __syncthreads();
    if (t == 0) {
        const int num_gt = s_ngt, num_pred = s_npred, pairs = s_pairs, ea = s_ea;
        int tp = 0;
        float seg_sum = 0.0f;
        // greedy matching in ascending gt-label order; a pred may match once
        for (int gl = 1; gl < LBL; ++gl) {
            int pl = best[gl];
            if (pl > 0 && !used[pl]) {
                int uni = gt_size[gl] + pred_size[pl] - inter[gl];
                if (uni < 1) uni = 1;
                seg_sum += (float)inter[gl] / (float)uni;
                used[pl] = 1;
                tp++;
            }
        }
        float ng = (float)(num_gt >= 1 ? num_gt : 1);
        float seg = seg_sum / ng;
        int ns = pairs - tp;
        int fn = num_gt - tp;
        int fp_ = num_pred - tp;
        float det = 1.0f - (float)(fp_ + fn + ns + ea) / ng;
        bool both_empty = (num_gt == 0) && (num_pred == 0);
        bool any_empty = (num_gt == 0) || (num_pred == 0);
        if (both_empty) { seg = 1.0f; det = 1.0f; }
        else if (any_empty) { seg = 0.0f; det = 0.0f; }
        out[0] = seg;
        out[1] = det;
    }
}

// ---------------- fallback path (tiny ws): direct atomics + full finalize ---
__global__ void hist_atomic_kernel(const int* __restrict__ pred, const int* __restrict__ gt,
                                   int* __restrict__ C, int n4, int n) {
    int idx = blockIdx.x * blockDim.x + threadIdx.x;
    int stride = gridDim.x * blockDim.x;
    const vint4* p4 = (const vint4*)pred;
    const vint4* g4 = (const vint4*)gt;
    for (int i = idx; i < n4; i += stride) {
        vint4 p = p4[i];
        vint4 g = g4[i];
        atomicAdd(&C[(g.x << 8) + p.x], 1);
        atomicAdd(&C[(g.y << 8) + p.y], 1);
        atomicAdd(&C[(g.z << 8) + p.z], 1);
        atomicAdd(&C[(g.w << 8) + p.w], 1);
    }
    if (idx == 0)
        for (int i = n4 * 4; i < n; ++i) atomicAdd(&C[(gt[i] << 8) + pred[i]], 1);
}

__global__ __launch_bounds__(1024)
void finalize_full_kernel(const int* __restrict__ C, float* __restrict__ out) {
    __shared__ int scratch[1024];
    __shared__ int gt_size[LBL], pred_size[LBL];
    __shared__ int best_p[LBL], inter_s[LBL], colcnt[LBL];
    __shared__ unsigned char has_s[LBL], used_s[LBL];
    __shared__ int s_pairs, s_ngt, s_npred, s_ea;
    const int t = threadIdx.x;
    if (t == 0) { s_pairs = 0; s_ngt = 0; s_npred = 0; s_ea = 0; }
    if (t < LBL) { best_p[t] = 0; inter_s[t] = 0; colcnt[t] = 0; has_s[t] = 0; used_s[t] = 0; }
    const int4* C4 = (const int4*)C;
    const int r = t >> 2, q = t & 3;
    int s = 0;
    #pragma unroll
    for (int j = 0; j < 16; ++j) {
        int4 v = C4[r * 64 + q * 16 + j];
        s += v.x + v.y + v.z + v.w;
    }
    scratch[t] = s;
    __syncthreads();
    if (t < LBL)
        gt_size[t] = scratch[4 * t] + scratch[4 * t + 1] + scratch[4 * t + 2] + scratch[4 * t + 3];
    __syncthreads();
    {
        const int c = t & 255, q2 = t >> 8;
        int cs = 0, cc = 0;
        #pragma unroll 8
        for (int g0 = 0; g0 < 64; ++g0) {
            int row = q2 * 64 + g0;
            int v = C[row * LBL + c];
            cs += v;
            cc += (row >= 1 && c >= 1 && v > 0) ? 1 : 0;
        }
        scratch[t] = cs;
        if (cc) atomicAdd(&colcnt[c], cc);
    }
    if (r >= 1) {
        const int gs = gt_size[r];
        int rp = 0;
        #pragma unroll
        for (int j = 0; j < 16; ++j) {
            int4 v = C4[r * 64 + q * 16 + j];
            int cb = q * 64 + 4 * j;
            if (cb >= 1) {
                if (v.x > 0) rp++;
                if (2 * v.x > gs) { has_s[r] = 1; best_p[r] = cb; inter_s[r] = v.x; }
            }
            if (v.y > 0) rp++;
            if (2 * v.y > gs) { has_s[r] = 1; best_p[r] = cb + 1; inter_s[r] = v.y; }
            if (v.z > 0) rp++;
            if (2 * v.z > gs) { has_s[r] = 1; best_p[r] = cb + 2; inter_s[r] = v.z; }
            if (v.w > 0) rp++;
            if (2 * v.w > gs) { has_s[r] = 1; best_p[r] = cb + 3; inter_s[r] = v.w; }
        }
        if (rp) atomicAdd(&s_pairs, rp);
    }
    __syncthreads();
    if (t < LBL)
        pred_size[t] = scratch[t] + scratch[256 + t] + scratch[512 + t] + scratch[768 + t];
    __syncthreads();
    if (t >= 1 && t < LBL) {
        if (gt_size[t] > 0) atomicAdd(&s_ngt, 1);
        if (pred_size[t] > 0) atomicAdd(&s_npred, 1);
        if (colcnt[t] > 1) atomicAdd(&s_ea, 1);
    }
    __syncthreads();
    if (t == 0) {
        const int num_gt = s_ngt, num_pred = s_npred, pairs = s_pairs, ea = s_ea;
        int tp = 0;
        float seg_sum = 0.0f;
        for (int gl = 1; gl < LBL; ++gl) {
            if (has_s[gl]) {
                int pl = best_p[gl];
                if (!used_s[pl]) {
                    int uni = gt_size[gl] + pred_size[pl] - inter_s[gl];
                    if (uni < 1) uni = 1;
                    seg_sum += (float)inter_s[gl] / (float)uni;
                    used_s[pl] = 1;
                    tp++;
                }
            }
        }
        float ng = (float)(num_gt >= 1 ? num_gt : 1);
        float seg = seg_sum / ng;
        int ns = pairs - tp;
        int fn = num_gt - tp;
        int fp_ = num_pred - tp;
        float det = 1.0f - (float)(fp_ + fn + ns + ea) / ng;
        bool both_empty = (num_gt == 0) && (num_pred == 0);
        bool any_empty = (num_gt == 0) || (num_pred == 0);
        if (both_empty) { seg = 1.0f; det = 1.0f; }
        else if (any_empty) { seg = 0.0f; det = 0.0f; }
        out[0] = seg;
        out[1] = det;
    }
}

extern "C" void kernel_launch(void* const* d_in, const int* in_sizes, int n_in,
                              void* d_out, int out_size, void* d_ws, size_t ws_size,
                              hipStream_t stream) {
    const int* pred = (const int*)d_in[0];
    const int* gt = (const int*)d_in[1];
    float* out = (float*)d_out;
    const int n = in_sizes[0];
    const int n4 = n / 4;

    const size_t part_bytes = (size_t)HIST_BLOCKS * NWORDS * sizeof(unsigned int);  // 32 MB
    const size_t aux_bytes = AUX_INTS * sizeof(int);
    if (ws_size >= part_bytes + aux_bytes) {
        unsigned int* partial = (unsigned int*)d_ws;
        int* aux = (int*)((char*)d_ws + part_bytes);
        hist_priv_kernel<<<HIST_BLOCKS, HIST_THREADS, 0, stream>>>(pred, gt, partial, aux, n4, n);
        reduce_finalize_kernel<<<LBL, 256, 0, stream>>>(partial, aux, out);
    } else {
        int* C = (int*)d_ws;
        (void)hipMemsetAsync(C, 0, (size_t)NBINS * sizeof(int), stream);
        hist_atomic_kernel<<<2048, 256, 0, stream>>>(pred, gt, C, n4, n);
        finalize_full_kernel<<<1, 1024, 0, stream>>>(C, out);
    }
}

// Round 6
// 172.025 us; speedup vs baseline: 1.0760x; 1.0760x over previous
//
#include <hip/hip_runtime.h>

#define LBL 256
#define NBINS (LBL * LBL)      // 65536 bins
#define NWORDS (NBINS / 2)     // 32768 packed u32 words (2 x u16 counters)
#define NQUADS (NWORDS / 4)    // 8192 uint4 quads (8 bins each)
#define HIST_BLOCKS 256
#define HIST_THREADS 1024

// aux layout (ints): [0]=ticket counter, [64..320)=colsum, [320..576)=colcnt,
// [576..832)=gt_size, [832..1088)=row_pairs, [1088..1344)=best_p, [1344..1600)=inter
#define AUX_COUNTER 0
#define AUX_COLSUM 64
#define AUX_COLCNT 320
#define AUX_GTSIZE 576
#define AUX_RP 832
#define AUX_BEST 1088
#define AUX_INTER 1344
#define AUX_ZERO_INTS 576      // only counter+colsum+colcnt need zeroing
#define AUX_INTS 1600

typedef int vint4 __attribute__((ext_vector_type(4)));

// ---------------- histogram with LDS privatization (packed u16 pairs) -------
// 128 KB static LDS -> 1 block/CU. Each block sees <= 65536 pixels, so a
// packed 16-bit half cannot overflow. Round-4 proven config: nontemporal
// loads (keep streaming inputs out of L2) + x4 manual unroll with named
// scalars (compiler keeps all 8 loads in flight).
__global__ __launch_bounds__(HIST_THREADS, 4)
void hist_priv_kernel(const int* __restrict__ pred, const int* __restrict__ gt,
                      unsigned int* __restrict__ partial, int* __restrict__ aux,
                      int n4, int n) {
    __shared__ unsigned int h[NWORDS];  // 128 KB
    const int t = threadIdx.x;
    if (blockIdx.x == 0 && t < AUX_ZERO_INTS) aux[t] = 0;  // consumer is next kernel
    #pragma unroll
    for (int i = t; i < NWORDS; i += HIST_THREADS) h[i] = 0u;
    __syncthreads();

    const vint4* p4 = (const vint4*)pred;
    const vint4* g4 = (const vint4*)gt;
    const int stride = HIST_BLOCKS * HIST_THREADS;
    int i = blockIdx.x * HIST_THREADS + t;
    for (; i + 3 * stride < n4; i += 4 * stride) {
        vint4 pa = __builtin_nontemporal_load(&p4[i]);
        vint4 ga = __builtin_nontemporal_load(&g4[i]);
        vint4 pb = __builtin_nontemporal_load(&p4[i + stride]);
        vint4 gb = __builtin_nontemporal_load(&g4[i + stride]);
        vint4 pc = __builtin_nontemporal_load(&p4[i + 2 * stride]);
        vint4 gc = __builtin_nontemporal_load(&g4[i + 2 * stride]);
        vint4 pd = __builtin_nontemporal_load(&p4[i + 3 * stride]);
        vint4 gd = __builtin_nontemporal_load(&g4[i + 3 * stride]);
        int b;
        b = (ga.x << 8) | pa.x; atomicAdd(&h[b >> 1], 1u << ((b & 1) << 4));
        b = (ga.y << 8) | pa.y; atomicAdd(&h[b >> 1], 1u << ((b & 1) << 4));
        b = (ga.z << 8) | pa.z; atomicAdd(&h[b >> 1], 1u << ((b & 1) << 4));
        b = (ga.w << 8) | pa.w; atomicAdd(&h[b >> 1], 1u << ((b & 1) << 4));
        b = (gb.x << 8) | pb.x; atomicAdd(&h[b >> 1], 1u << ((b & 1) << 4));
        b = (gb.y << 8) | pb.y; atomicAdd(&h[b >> 1], 1u << ((b & 1) << 4));
        b = (gb.z << 8) | pb.z; atomicAdd(&h[b >> 1], 1u << ((b & 1) << 4));
        b = (gb.w << 8) | pb.w; atomicAdd(&h[b >> 1], 1u << ((b & 1) << 4));
        b = (gc.x << 8) | pc.x; atomicAdd(&h[b >> 1], 1u << ((b & 1) << 4));
        b = (gc.y << 8) | pc.y; atomicAdd(&h[b >> 1], 1u << ((b & 1) << 4));
        b = (gc.z << 8) | pc.z; atomicAdd(&h[b >> 1], 1u << ((b & 1) << 4));
        b = (gc.w << 8) | pc.w; atomicAdd(&h[b >> 1], 1u << ((b & 1) << 4));
        b = (gd.x << 8) | pd.x; atomicAdd(&h[b >> 1], 1u << ((b & 1) << 4));
        b = (gd.y << 8) | pd.y; atomicAdd(&h[b >> 1], 1u << ((b & 1) << 4));
        b = (gd.z << 8) | pd.z; atomicAdd(&h[b >> 1], 1u << ((b & 1) << 4));
        b = (gd.w << 8) | pd.w; atomicAdd(&h[b >> 1], 1u << ((b & 1) << 4));
    }
    for (; i < n4; i += stride) {
        vint4 p = p4[i];
        vint4 g = g4[i];
        int b;
        b = (g.x << 8) | p.x; atomicAdd(&h[b >> 1], 1u << ((b & 1) << 4));
        b = (g.y << 8) | p.y; atomicAdd(&h[b >> 1], 1u << ((b & 1) << 4));
        b = (g.z << 8) | p.z; atomicAdd(&h[b >> 1], 1u << ((b & 1) << 4));
        b = (g.w << 8) | p.w; atomicAdd(&h[b >> 1], 1u << ((b & 1) << 4));
    }
    if (blockIdx.x == 0 && t == 0) {  // n%4 tail — dead for 4096x4096
        for (int j = n4 * 4; j < n; ++j) {
            int b = (gt[j] << 8) | pred[j];
            atomicAdd(&h[b >> 1], 1u << ((b & 1) << 4));
        }
    }
    __syncthreads();
    uint4* dst = (uint4*)(partial + (size_t)blockIdx.x * NWORDS);
    const uint4* src = (const uint4*)h;
    #pragma unroll
    for (int j = t; j < NQUADS; j += HIST_THREADS) dst[j] = src[j];
}

// ---------------- fused reduce + finalize (last-block pattern) --------------
// Block r sums the 256 packed partials for row r of C, does the row-side
// analysis (gt_size, Cnz pair count, majority match), atomicAdds its column
// contributions into aux colsum/colcnt, publishes row meta, then takes a
// ticket. The last-arriving block (all 256 rows complete) performs tallies
// and the greedy matching. No spin-wait -> no co-residency assumption.
__global__ __launch_bounds__(256)
void reduce_finalize_kernel(const unsigned int* __restrict__ partial,
                            int* __restrict__ aux, float* __restrict__ out) {
    __shared__ int acc[256];
    __shared__ int red[4], redp[4];
    __shared__ int s_gs, s_rp, s_best, s_inter, s_last;
    const int t = threadIdx.x;
    const int r = blockIdx.x;
    acc[t] = 0;
    if (t == 0) { s_best = 0; s_inter = 0; }
    __syncthreads();

    // sum 256 partials for this row's 32 quads (8 bins/quad)
    const int qlocal = t & 31;            // quad within row
    const int q = r * 32 + qlocal;        // global quad index
    const int pg = t >> 5;                // partial group 0..7 (32 partials each)
    const uint4* p4 = (const uint4*)partial;
    int s0 = 0, s1 = 0, s2 = 0, s3 = 0, s4 = 0, s5 = 0, s6 = 0, s7 = 0;
    #pragma unroll 8
    for (int k = 0; k < 32; ++k) {
        uint4 v = p4[(size_t)(pg * 32 + k) * NQUADS + q];
        s0 += (int)(v.x & 0xFFFFu); s1 += (int)(v.x >> 16);
        s2 += (int)(v.y & 0xFFFFu); s3 += (int)(v.y >> 16);
        s4 += (int)(v.z & 0xFFFFu); s5 += (int)(v.z >> 16);
        s6 += (int)(v.w & 0xFFFFu); s7 += (int)(v.w >> 16);
    }
    const int cb = qlocal * 8;
    atomicAdd(&acc[cb + 0], s0); atomicAdd(&acc[cb + 1], s1);
    atomicAdd(&acc[cb + 2], s2); atomicAdd(&acc[cb + 3], s3);
    atomicAdd(&acc[cb + 4], s4); atomicAdd(&acc[cb + 5], s5);
    atomicAdd(&acc[cb + 6], s6); atomicAdd(&acc[cb + 7], s7);
    __syncthreads();

    const int v = acc[t];                 // this row's count at col t
    // column-side accumulators (device-scope atomics; coherent at fabric point)
    if (v) atomicAdd(&aux[AUX_COLSUM + t], v);
    if (r >= 1 && t >= 1 && v > 0) atomicAdd(&aux[AUX_COLCNT + t], 1);

    // row reductions: full row sum (gt_size) + Cnz pair count
    int ssum = v;
    int pcnt = (r >= 1 && t >= 1 && v > 0) ? 1 : 0;
    #pragma unroll
    for (int m = 32; m >= 1; m >>= 1) {
        ssum += __shfl_xor(ssum, m);
        pcnt += __shfl_xor(pcnt, m);
    }
    if ((t & 63) == 0) { red[t >> 6] = ssum; redp[t >> 6] = pcnt; }
    __syncthreads();
    if (t == 0) {
        s_gs = red[0] + red[1] + red[2] + red[3];
        s_rp = redp[0] + redp[1] + redp[2] + redp[3];
    }
    __syncthreads();
    // at most one col can satisfy 2v > gs (two would sum past gs) -> plain store
    if (r >= 1 && t >= 1 && 2 * v > s_gs) { s_best = t; s_inter = v; }
    __syncthreads();
    // publish row meta, then take a ticket. __syncthreads above drained this
    // block's atomics (vmcnt(0) before s_barrier); fence orders t0's stores.
    if (t == 0) {
        aux[AUX_GTSIZE + r] = s_gs;
        aux[AUX_RP + r] = s_rp;
        aux[AUX_BEST + r] = s_best;
        aux[AUX_INTER + r] = s_inter;
        __threadfence();
        int ticket = atomicAdd(&aux[AUX_COUNTER], 1);
        s_last = (ticket == (int)gridDim.x - 1) ? 1 : 0;
    }
    __syncthreads();
    if (!s_last) return;
    __threadfence();  // acquire side

    // ---------------- finalize in the last block ----------------
    __shared__ int gt_size[LBL], pred_size[LBL], best[LBL], inter[LBL];
    __shared__ int rp_a[LBL], colcnt[LBL];
    __shared__ unsigned char used[LBL];
    __shared__ int s_ngt, s_npred, s_pairs, s_ea;
    if (t == 0) { s_ngt = 0; s_npred = 0; s_pairs = 0; s_ea = 0; }
    used[t & 255] = 0;
    gt_size[t]   = __hip_atomic_load(&aux[AUX_GTSIZE + t], __ATOMIC_RELAXED, __HIP_MEMORY_SCOPE_AGENT);
    rp_a[t]      = __hip_atomic_load(&aux[AUX_RP + t],     __ATOMIC_RELAXED, __HIP_MEMORY_SCOPE_AGENT);
    best[t]      = __hip_atomic_load(&aux[AUX_BEST + t],   __ATOMIC_RELAXED, __HIP_MEMORY_SCOPE_AGENT);
    inter[t]     = __hip_atomic_load(&aux[AUX_INTER + t],  __ATOMIC_RELAXED, __HIP_MEMORY_SCOPE_AGENT);
    pred_size[t] = __hip_atomic_load(&aux[AUX_COLSUM + t], __ATOMIC_RELAXED, __HIP_MEMORY_SCOPE_AGENT);
    colcnt[t]    = __hip_atomic_load(&aux[AUX_COLCNT + t], __ATOMIC_RELAXED, __HIP_MEMORY_SCOPE_AGENT);
    __syncthreads();
    if (t >= 1) {
        if (gt_size[t] > 0) atomicAdd(&s_ngt, 1);
        if (pred_size[t] > 0) atomicAdd(&s_npred, 1);
        if (colcnt[t] > 1) atomicAdd(&s_ea, 1);
        if (rp_a[t]) atomicAdd(&s_pairs, rp_a[t]);
    }
    __syncthreads();
    if (t == 0) {
        const int num_gt = s_ngt, num_pred = s_npred, pairs = s_pairs, ea = s_ea;
        int tp = 0;
        float seg_sum = 0.0f;
        // greedy matching in ascending gt-label order; a pred may match once
        for (int gl = 1; gl < LBL; ++gl) {
            int pl = best[gl];
            if (pl > 0 && !used[pl]) {
                int uni = gt_size[gl] + pred_size[pl] - inter[gl];
                if (uni < 1) uni = 1;
                seg_sum += (float)inter[gl] / (float)uni;
                used[pl] = 1;
                tp++;
            }
        }
        float ng = (float)(num_gt >= 1 ? num_gt : 1);
        float seg = seg_sum / ng;
        int ns = pairs - tp;
        int fn = num_gt - tp;
        int fp_ = num_pred - tp;
        float det = 1.0f - (float)(fp_ + fn + ns + ea) / ng;
        bool both_empty = (num_gt == 0) && (num_pred == 0);
        bool any_empty = (num_gt == 0) || (num_pred == 0);
        if (both_empty) { seg = 1.0f; det = 1.0f; }
        else if (any_empty) { seg = 0.0f; det = 0.0f; }
        out[0] = seg;
        out[1] = det;
    }
}

// ---------------- fallback path (tiny ws): direct atomics + full finalize ---
__global__ void hist_atomic_kernel(const int* __restrict__ pred, const int* __restrict__ gt,
                                   int* __restrict__ C, int n4, int n) {
    int idx = blockIdx.x * blockDim.x + threadIdx.x;
    int stride = gridDim.x * blockDim.x;
    const vint4* p4 = (const vint4*)pred;
    const vint4* g4 = (const vint4*)gt;
    for (int i = idx; i < n4; i += stride) {
        vint4 p = p4[i];
        vint4 g = g4[i];
        atomicAdd(&C[(g.x << 8) + p.x], 1);
        atomicAdd(&C[(g.y << 8) + p.y], 1);
        atomicAdd(&C[(g.z << 8) + p.z], 1);
        atomicAdd(&C[(g.w << 8) + p.w], 1);
    }
    if (idx == 0)
        for (int i = n4 * 4; i < n; ++i) atomicAdd(&C[(gt[i] << 8) + pred[i]], 1);
}

__global__ __launch_bounds__(1024)
void finalize_full_kernel(const int* __restrict__ C, float* __restrict__ out) {
    __shared__ int scratch[1024];
    __shared__ int gt_size[LBL], pred_size[LBL];
    __shared__ int best_p[LBL], inter_s[LBL], colcnt[LBL];
    __shared__ unsigned char has_s[LBL], used_s[LBL];
    __shared__ int s_pairs, s_ngt, s_npred, s_ea;
    const int t = threadIdx.x;
    if (t == 0) { s_pairs = 0; s_ngt = 0; s_npred = 0; s_ea = 0; }
    if (t < LBL) { best_p[t] = 0; inter_s[t] = 0; colcnt[t] = 0; has_s[t] = 0; used_s[t] = 0; }
    const int4* C4 = (const int4*)C;
    const int r = t >> 2, q = t & 3;
    int s = 0;
    #pragma unroll
    for (int j = 0; j < 16; ++j) {
        int4 v = C4[r * 64 + q * 16 + j];
        s += v.x + v.y + v.z + v.w;
    }
    scratch[t] = s;
    __syncthreads();
    if (t < LBL)
        gt_size[t] = scratch[4 * t] + scratch[4 * t + 1] + scratch[4 * t + 2] + scratch[4 * t + 3];
    __syncthreads();
    {
        const int c = t & 255, q2 = t >> 8;
        int cs = 0, cc = 0;
        #pragma unroll 8
        for (int g0 = 0; g0 < 64; ++g0) {
            int row = q2 * 64 + g0;
            int v = C[row * LBL + c];
            cs += v;
            cc += (row >= 1 && c >= 1 && v > 0) ? 1 : 0;
        }
        scratch[t] = cs;
        if (cc) atomicAdd(&colcnt[c], cc);
    }
    if (r >= 1) {
        const int gs = gt_size[r];
        int rp = 0;
        #pragma unroll
        for (int j = 0; j < 16; ++j) {
            int4 v = C4[r * 64 + q * 16 + j];
            int cb = q * 64 + 4 * j;
            if (cb >= 1) {
                if (v.x > 0) rp++;
                if (2 * v.x > gs) { has_s[r] = 1; best_p[r] = cb; inter_s[r] = v.x; }
            }
            if (v.y > 0) rp++;
            if (2 * v.y > gs) { has_s[r] = 1; best_p[r] = cb + 1; inter_s[r] = v.y; }
            if (v.z > 0) rp++;
            if (2 * v.z > gs) { has_s[r] = 1; best_p[r] = cb + 2; inter_s[r] = v.z; }
            if (v.w > 0) rp++;
            if (2 * v.w > gs) { has_s[r] = 1; best_p[r] = cb + 3; inter_s[r] = v.w; }
        }
        if (rp) atomicAdd(&s_pairs, rp);
    }
    __syncthreads();
    if (t < LBL)
        pred_size[t] = scratch[t] + scratch[256 + t] + scratch[512 + t] + scratch[768 + t];
    __syncthreads();
    if (t >= 1 && t < LBL) {
        if (gt_size[t] > 0) atomicAdd(&s_ngt, 1);
        if (pred_size[t] > 0) atomicAdd(&s_npred, 1);
        if (colcnt[t] > 1) atomicAdd(&s_ea, 1);
    }
    __syncthreads();
    if (t == 0) {
        const int num_gt = s_ngt, num_pred = s_npred, pairs = s_pairs, ea = s_ea;
        int tp = 0;
        float seg_sum = 0.0f;
        for (int gl = 1; gl < LBL; ++gl) {
            if (has_s[gl]) {
                int pl = best_p[gl];
                if (!used_s[pl]) {
                    int uni = gt_size[gl] + pred_size[pl] - inter_s[gl];
                    if (uni < 1) uni = 1;
                    seg_sum += (float)inter_s[gl] / (float)uni;
                    used_s[pl] = 1;
                    tp++;
                }
            }
        }
        float ng = (float)(num_gt >= 1 ? num_gt : 1);
        float seg = seg_sum / ng;
        int ns = pairs - tp;
        int fn = num_gt - tp;
        int fp_ = num_pred - tp;
        float det = 1.0f - (float)(fp_ + fn + ns + ea) / ng;
        bool both_empty = (num_gt == 0) && (num_pred == 0);
        bool any_empty = (num_gt == 0) || (num_pred == 0);
        if (both_empty) { seg = 1.0f; det = 1.0f; }
        else if (any_empty) { seg = 0.0f; det = 0.0f; }
        out[0] = seg;
        out[1] = det;
    }
}

extern "C" void kernel_launch(void* const* d_in, const int* in_sizes, int n_in,
                              void* d_out, int out_size, void* d_ws, size_t ws_size,
                              hipStream_t stream) {
    const int* pred = (const int*)d_in[0];
    const int* gt = (const int*)d_in[1];
    float* out = (float*)d_out;
    const int n = in_sizes[0];
    const int n4 = n / 4;

    const size_t part_bytes = (size_t)HIST_BLOCKS * NWORDS * sizeof(unsigned int);  // 32 MB
    const size_t aux_bytes = AUX_INTS * sizeof(int);
    if (ws_size >= part_bytes + aux_bytes) {
        unsigned int* partial = (unsigned int*)d_ws;
        int* aux = (int*)((char*)d_ws + part_bytes);
        hist_priv_kernel<<<HIST_BLOCKS, HIST_THREADS, 0, stream>>>(pred, gt, partial, aux, n4, n);
        reduce_finalize_kernel<<<LBL, 256, 0, stream>>>(partial, aux, out);
    } else {
        int* C = (int*)d_ws;
        (void)hipMemsetAsync(C, 0, (size_t)NBINS * sizeof(int), stream);
        hist_atomic_kernel<<<2048, 256, 0, stream>>>(pred, gt, C, n4, n);
        finalize_full_kernel<<<1, 1024, 0, stream>>>(C, out);
    }
}

// Round 7
// 172.002 us; speedup vs baseline: 1.0762x; 1.0001x over previous
//
#include <hip/hip_runtime.h>

#define LBL 256
#define NBINS (LBL * LBL)      // 65536 bins
#define NWORDS (NBINS / 2)     // 32768 packed u32 words (2 x u16 counters)
#define NQUADS (NWORDS / 4)    // 8192 uint4 quads (8 bins each)
#define HIST_BLOCKS 256
#define HIST_THREADS 1024

// aux layout (ints): [0]=ticket counter, [64..320)=colsum, [320..576)=colcnt,
// [576..832)=gt_size, [832..1088)=row_pairs, [1088..1344)=best_p, [1344..1600)=inter
#define AUX_COUNTER 0
#define AUX_COLSUM 64
#define AUX_COLCNT 320
#define AUX_GTSIZE 576
#define AUX_RP 832
#define AUX_BEST 1088
#define AUX_INTER 1344
#define AUX_ZERO_INTS 576      // only counter+colsum+colcnt need zeroing
#define AUX_INTS 1600

typedef int vint4 __attribute__((ext_vector_type(4)));

#define LOADPAIR(v, idx) \
    vint4 p##v = __builtin_nontemporal_load(&p4[idx]); \
    vint4 g##v = __builtin_nontemporal_load(&g4[idx]);
#define PROC(v) { int b; \
    b = (g##v.x << 8) | p##v.x; atomicAdd(&h[b >> 1], 1u << ((b & 1) << 4)); \
    b = (g##v.y << 8) | p##v.y; atomicAdd(&h[b >> 1], 1u << ((b & 1) << 4)); \
    b = (g##v.z << 8) | p##v.z; atomicAdd(&h[b >> 1], 1u << ((b & 1) << 4)); \
    b = (g##v.w << 8) | p##v.w; atomicAdd(&h[b >> 1], 1u << ((b & 1) << 4)); }

// ---------------- histogram with LDS privatization (packed u16 pairs) -------
// 128 KB static LDS -> 1 block/CU. Each block sees <= 65536 pixels, so a
// packed 16-bit half cannot overflow. NT loads keep the streaming inputs
// from evicting L2. x8 unroll with NAMED scalars: 16 independent 16B loads
// in flight per thread (r5's array form serialized at VGPR=52; named form
// forces ~100 VGPRs of live loads, still under the 128 cap of (1024,4)).
__global__ __launch_bounds__(HIST_THREADS, 4)
void hist_priv_kernel(const int* __restrict__ pred, const int* __restrict__ gt,
                      unsigned int* __restrict__ partial, int* __restrict__ aux,
                      int n4, int n) {
    __shared__ unsigned int h[NWORDS];  // 128 KB
    const int t = threadIdx.x;
    if (blockIdx.x == 0 && t < AUX_ZERO_INTS) aux[t] = 0;  // consumer is next kernel
    #pragma unroll
    for (int i = t; i < NWORDS; i += HIST_THREADS) h[i] = 0u;
    __syncthreads();

    const vint4* p4 = (const vint4*)pred;
    const vint4* g4 = (const vint4*)gt;
    const int stride = HIST_BLOCKS * HIST_THREADS;
    int i = blockIdx.x * HIST_THREADS + t;
    for (; i + 7 * stride < n4; i += 8 * stride) {
        LOADPAIR(a, i)
        LOADPAIR(b2, i + stride)
        LOADPAIR(c, i + 2 * stride)
        LOADPAIR(d, i + 3 * stride)
        LOADPAIR(e, i + 4 * stride)
        LOADPAIR(f, i + 5 * stride)
        LOADPAIR(g2, i + 6 * stride)
        LOADPAIR(h2, i + 7 * stride)
        PROC(a) PROC(b2) PROC(c) PROC(d) PROC(e) PROC(f) PROC(g2) PROC(h2)
    }
    for (; i + 3 * stride < n4; i += 4 * stride) {
        LOADPAIR(a, i)
        LOADPAIR(b2, i + stride)
        LOADPAIR(c, i + 2 * stride)
        LOADPAIR(d, i + 3 * stride)
        PROC(a) PROC(b2) PROC(c) PROC(d)
    }
    for (; i < n4; i += stride) {
        LOADPAIR(a, i)
        PROC(a)
    }
    if (blockIdx.x == 0 && t == 0) {  // n%4 tail — dead for 4096x4096
        for (int j = n4 * 4; j < n; ++j) {
            int b = (gt[j] << 8) | pred[j];
            atomicAdd(&h[b >> 1], 1u << ((b & 1) << 4));
        }
    }
    __syncthreads();
    uint4* dst = (uint4*)(partial + (size_t)blockIdx.x * NWORDS);
    const uint4* src = (const uint4*)h;
    #pragma unroll
    for (int j = t; j < NQUADS; j += HIST_THREADS) dst[j] = src[j];
}

// ---------------- fused reduce + finalize (last-block pattern) --------------
// 1024 threads: thread (qlocal=t&31, sub=t>>5) sums 8 partials for its quad
// (4x more load parallelism than the 256-thread version), LDS-atomics into
// the row accumulator. Row analysis + greedy as before on t<256. Last block
// (ticket) finalizes. No spin-wait -> no co-residency assumption.
__global__ __launch_bounds__(1024)
void reduce_finalize_kernel(const unsigned int* __restrict__ partial,
                            int* __restrict__ aux, float* __restrict__ out) {
    __shared__ int acc[256];
    __shared__ int red[4], redp[4];
    __shared__ int s_gs, s_rp, s_best, s_inter, s_last;
    const int t = threadIdx.x;
    const int r = blockIdx.x;
    if (t < 256) acc[t] = 0;
    if (t == 0) { s_best = 0; s_inter = 0; }
    __syncthreads();

    const int qlocal = t & 31;            // quad within row (32 quads = 256 bins)
    const int q = r * 32 + qlocal;        // global quad index
    const int sub = t >> 5;               // 0..31, 8 partials each
    const uint4* p4 = (const uint4*)partial;
    int s0 = 0, s1 = 0, s2 = 0, s3 = 0, s4 = 0, s5 = 0, s6 = 0, s7 = 0;
    #pragma unroll
    for (int k = 0; k < 8; ++k) {
        uint4 v = p4[(size_t)(sub * 8 + k) * NQUADS + q];
        s0 += (int)(v.x & 0xFFFFu); s1 += (int)(v.x >> 16);
        s2 += (int)(v.y & 0xFFFFu); s3 += (int)(v.y >> 16);
        s4 += (int)(v.z & 0xFFFFu); s5 += (int)(v.z >> 16);
        s6 += (int)(v.w & 0xFFFFu); s7 += (int)(v.w >> 16);
    }
    const int cb = qlocal * 8;
    atomicAdd(&acc[cb + 0], s0); atomicAdd(&acc[cb + 1], s1);
    atomicAdd(&acc[cb + 2], s2); atomicAdd(&acc[cb + 3], s3);
    atomicAdd(&acc[cb + 4], s4); atomicAdd(&acc[cb + 5], s5);
    atomicAdd(&acc[cb + 6], s6); atomicAdd(&acc[cb + 7], s7);
    __syncthreads();

    if (t < 256) {
        const int v = acc[t];             // this row's count at col t
        // column-side accumulators (device-scope atomics; coherent at fabric)
        if (v) atomicAdd(&aux[AUX_COLSUM + t], v);
        if (r >= 1 && t >= 1 && v > 0) atomicAdd(&aux[AUX_COLCNT + t], 1);

        // row reductions: full row sum (gt_size) + Cnz pair count
        int ssum = v;
        int pcnt = (r >= 1 && t >= 1 && v > 0) ? 1 : 0;
        #pragma unroll
        for (int m = 32; m >= 1; m >>= 1) {
            ssum += __shfl_xor(ssum, m);
            pcnt += __shfl_xor(pcnt, m);
        }
        if ((t & 63) == 0) { red[t >> 6] = ssum; redp[t >> 6] = pcnt; }
    }
    __syncthreads();
    if (t == 0) {
        s_gs = red[0] + red[1] + red[2] + red[3];
        s_rp = redp[0] + redp[1] + redp[2] + redp[3];
    }
    __syncthreads();
    // at most one col can satisfy 2v > gs (two would sum past gs) -> plain store
    if (t < 256 && r >= 1 && t >= 1 && 2 * acc[t] > s_gs) { s_best = t; s_inter = acc[t]; }
    __syncthreads();
    // publish row meta, then take a ticket. __syncthreads above drained this
    // block's atomics (vmcnt(0) before s_barrier); fence orders t0's stores.
    if (t == 0) {
        aux[AUX_GTSIZE + r] = s_gs;
        aux[AUX_RP + r] = s_rp;
        aux[AUX_BEST + r] = s_best;
        aux[AUX_INTER + r] = s_inter;
        __threadfence();
        int ticket = atomicAdd(&aux[AUX_COUNTER], 1);
        s_last = (ticket == (int)gridDim.x - 1) ? 1 : 0;
    }
    __syncthreads();
    if (!s_last) return;
    __threadfence();  // acquire side

    // ---------------- finalize in the last block ----------------
    __shared__ int gt_size[LBL], pred_size[LBL], best[LBL], inter[LBL];
    __shared__ int rp_a[LBL], colcnt[LBL];
    __shared__ unsigned char used[LBL];
    __shared__ int s_ngt, s_npred, s_pairs, s_ea;
    if (t == 0) { s_ngt = 0; s_npred = 0; s_pairs = 0; s_ea = 0; }
    if (t < 256) {
        used[t] = 0;
        gt_size[t]   = __hip_atomic_load(&aux[AUX_GTSIZE + t], __ATOMIC_RELAXED, __HIP_MEMORY_SCOPE_AGENT);
        rp_a[t]      = __hip_atomic_load(&aux[AUX_RP + t],     __ATOMIC_RELAXED, __HIP_MEMORY_SCOPE_AGENT);
        best[t]      = __hip_atomic_load(&aux[AUX_BEST + t],   __ATOMIC_RELAXED, __HIP_MEMORY_SCOPE_AGENT);
        inter[t]     = __hip_atomic_load(&aux[AUX_INTER + t],  __ATOMIC_RELAXED, __HIP_MEMORY_SCOPE_AGENT);
        pred_size[t] = __hip_atomic_load(&aux[AUX_COLSUM + t], __ATOMIC_RELAXED, __HIP_MEMORY_SCOPE_AGENT);
        colcnt[t]    = __hip_atomic_load(&aux[AUX_COLCNT + t], __ATOMIC_RELAXED, __HIP_MEMORY_SCOPE_AGENT);
    }
    __syncthreads();
    if (t >= 1 && t < 256) {
        if (gt_size[t] > 0) atomicAdd(&s_ngt, 1);
        if (pred_size[t] > 0) atomicAdd(&s_npred, 1);
        if (colcnt[t] > 1) atomicAdd(&s_ea, 1);
        if (rp_a[t]) atomicAdd(&s_pairs, rp_a[t]);
    }
    __syncthreads();
    if (t == 0) {
        const int num_gt = s_ngt, num_pred = s_npred, pairs = s_pairs, ea = s_ea;
        int tp = 0;
        float seg_sum = 0.0f;
        // greedy matching in ascending gt-label order; a pred may match once
        for (int gl = 1; gl < LBL; ++gl) {
            int pl = best[gl];
            if (pl > 0 && !used[pl]) {
                int uni = gt_size[gl] + pred_size[pl] - inter[gl];
                if (uni < 1) uni = 1;
                seg_sum += (float)inter[gl] / (float)uni;
                used[pl] = 1;
                tp++;
            }
        }
        float ng = (float)(num_gt >= 1 ? num_gt : 1);
        float seg = seg_sum / ng;
        int ns = pairs - tp;
        int fn = num_gt - tp;
        int fp_ = num_pred - tp;
        float det = 1.0f - (float)(fp_ + fn + ns + ea) / ng;
        bool both_empty = (num_gt == 0) && (num_pred == 0);
        bool any_empty = (num_gt == 0) || (num_pred == 0);
        if (both_empty) { seg = 1.0f; det = 1.0f; }
        else if (any_empty) { seg = 0.0f; det = 0.0f; }
        out[0] = seg;
        out[1] = det;
    }
}

// ---------------- fallback path (tiny ws): direct atomics + full finalize ---
__global__ void hist_atomic_kernel(const int* __restrict__ pred, const int* __restrict__ gt,
                                   int* __restrict__ C, int n4, int n) {
    int idx = blockIdx.x * blockDim.x + threadIdx.x;
    int stride = gridDim.x * blockDim.x;
    const vint4* p4 = (const vint4*)pred;
    const vint4* g4 = (const vint4*)gt;
    for (int i = idx; i < n4; i += stride) {
        vint4 p = p4[i];
        vint4 g = g4[i];
        atomicAdd(&C[(g.x << 8) + p.x], 1);
        atomicAdd(&C[(g.y << 8) + p.y], 1);
        atomicAdd(&C[(g.z << 8) + p.z], 1);
        atomicAdd(&C[(g.w << 8) + p.w], 1);
    }
    if (idx == 0)
        for (int i = n4 * 4; i < n; ++i) atomicAdd(&C[(gt[i] << 8) + pred[i]], 1);
}

__global__ __launch_bounds__(1024)
void finalize_full_kernel(const int* __restrict__ C, float* __restrict__ out) {
    __shared__ int scratch[1024];
    __shared__ int gt_size[LBL], pred_size[LBL];
    __shared__ int best_p[LBL], inter_s[LBL], colcnt[LBL];
    __shared__ unsigned char has_s[LBL], used_s[LBL];
    __shared__ int s_pairs, s_ngt, s_npred, s_ea;
    const int t = threadIdx.x;
    if (t == 0) { s_pairs = 0; s_ngt = 0; s_npred = 0; s_ea = 0; }
    if (t < LBL) { best_p[t] = 0; inter_s[t] = 0; colcnt[t] = 0; has_s[t] = 0; used_s[t] = 0; }
    const int4* C4 = (const int4*)C;
    const int r = t >> 2, q = t & 3;
    int s = 0;
    #pragma unroll
    for (int j = 0; j < 16; ++j) {
        int4 v = C4[r * 64 + q * 16 + j];
        s += v.x + v.y + v.z + v.w;
    }
    scratch[t] = s;
    __syncthreads();
    if (t < LBL)
        gt_size[t] = scratch[4 * t] + scratch[4 * t + 1] + scratch[4 * t + 2] + scratch[4 * t + 3];
    __syncthreads();
    {
        const int c = t & 255, q2 = t >> 8;
        int cs = 0, cc = 0;
        #pragma unroll 8
        for (int g0 = 0; g0 < 64; ++g0) {
            int row = q2 * 64 + g0;
            int v = C[row * LBL + c];
            cs += v;
            cc += (row >= 1 && c >= 1 && v > 0) ? 1 : 0;
        }
        scratch[t] = cs;
        if (cc) atomicAdd(&colcnt[c], cc);
    }
    if (r >= 1) {
        const int gs = gt_size[r];
        int rp = 0;
        #pragma unroll
        for (int j = 0; j < 16; ++j) {
            int4 v = C4[r * 64 + q * 16 + j];
            int cb = q * 64 + 4 * j;
            if (cb >= 1) {
                if (v.x > 0) rp++;
                if (2 * v.x > gs) { has_s[r] = 1; best_p[r] = cb; inter_s[r] = v.x; }
            }
            if (v.y > 0) rp++;
            if (2 * v.y > gs) { has_s[r] = 1; best_p[r] = cb + 1; inter_s[r] = v.y; }
            if (v.z > 0) rp++;
            if (2 * v.z > gs) { has_s[r] = 1; best_p[r] = cb + 2; inter_s[r] = v.z; }
            if (v.w > 0) rp++;
            if (2 * v.w > gs) { has_s[r] = 1; best_p[r] = cb + 3; inter_s[r] = v.w; }
        }
        if (rp) atomicAdd(&s_pairs, rp);
    }
    __syncthreads();
    if (t < LBL)
        pred_size[t] = scratch[t] + scratch[256 + t] + scratch[512 + t] + scratch[768 + t];
    __syncthreads();
    if (t >= 1 && t < LBL) {
        if (gt_size[t] > 0) atomicAdd(&s_ngt, 1);
        if (pred_size[t] > 0) atomicAdd(&s_npred, 1);
        if (colcnt[t] > 1) atomicAdd(&s_ea, 1);
    }
    __syncthreads();
    if (t == 0) {
        const int num_gt = s_ngt, num_pred = s_npred, pairs = s_pairs, ea = s_ea;
        int tp = 0;
        float seg_sum = 0.0f;
        for (int gl = 1; gl < LBL; ++gl) {
            if (has_s[gl]) {
                int pl = best_p[gl];
                if (!used_s[pl]) {
                    int uni = gt_size[gl] + pred_size[pl] - inter_s[gl];
                    if (uni < 1) uni = 1;
                    seg_sum += (float)inter_s[gl] / (float)uni;
                    used_s[pl] = 1;
                    tp++;
                }
            }
        }
        float ng = (float)(num_gt >= 1 ? num_gt : 1);
        float seg = seg_sum / ng;
        int ns = pairs - tp;
        int fn = num_gt - tp;
        int fp_ = num_pred - tp;
        float det = 1.0f - (float)(fp_ + fn + ns + ea) / ng;
        bool both_empty = (num_gt == 0) && (num_pred == 0);
        bool any_empty = (num_gt == 0) || (num_pred == 0);
        if (both_empty) { seg = 1.0f; det = 1.0f; }
        else if (any_empty) { seg = 0.0f; det = 0.0f; }
        out[0] = seg;
        out[1] = det;
    }
}

extern "C" void kernel_launch(void* const* d_in, const int* in_sizes, int n_in,
                              void* d_out, int out_size, void* d_ws, size_t ws_size,
                              hipStream_t stream) {
    const int* pred = (const int*)d_in[0];
    const int* gt = (const int*)d_in[1];
    float* out = (float*)d_out;
    const int n = in_sizes[0];
    const int n4 = n / 4;

    const size_t part_bytes = (size_t)HIST_BLOCKS * NWORDS * sizeof(unsigned int);  // 32 MB
    const size_t aux_bytes = AUX_INTS * sizeof(int);
    if (ws_size >= part_bytes + aux_bytes) {
        unsigned int* partial = (unsigned int*)d_ws;
        int* aux = (int*)((char*)d_ws + part_bytes);
        hist_priv_kernel<<<HIST_BLOCKS, HIST_THREADS, 0, stream>>>(pred, gt, partial, aux, n4, n);
        reduce_finalize_kernel<<<LBL, 1024, 0, stream>>>(partial, aux, out);
    } else {
        int* C = (int*)d_ws;
        (void)hipMemsetAsync(C, 0, (size_t)NBINS * sizeof(int), stream);
        hist_atomic_kernel<<<2048, 256, 0, stream>>>(pred, gt, C, n4, n);
        finalize_full_kernel<<<1, 1024, 0, stream>>>(C, out);
    }
}